// Round 1
// baseline (906.510 us; speedup 1.0000x reference)
//
#include <hip/hip_runtime.h>
#include <cstdint>
#include <cstddef>

typedef unsigned short u16;
typedef __attribute__((ext_vector_type(8))) short short8;
typedef __attribute__((ext_vector_type(4))) float floatx4;

static __device__ __forceinline__ u16 f2bf(float f){
  union { float f; uint32_t i; } u; u.f = f;
  uint32_t i = u.i;
  return (u16)((i + 0x7FFFu + ((i >> 16) & 1u)) >> 16);
}

struct __align__(8) U16x4 { u16 a,b,c,d; };

// ---------------- elementwise fp32 -> bf16 ----------------
__global__ void k_convert(const float* __restrict__ src, u16* __restrict__ dst, int n4){
  int i = blockIdx.x*256 + threadIdx.x;
  if (i >= n4) return;
  float4 v = ((const float4*)src)[i];
  U16x4 o{f2bf(v.x), f2bf(v.y), f2bf(v.z), f2bf(v.w)};
  ((U16x4*)dst)[i] = o;
}

// past_k [16][4096][128] fp32 -> kcat [16][4608][128] bf16 rows 0..4095
__global__ void k_copy_pastk(const float* __restrict__ pk, u16* __restrict__ kcat){
  int i = blockIdx.x*256 + threadIdx.x;   // float4 index, 2,097,152 total
  int slice = i >> 17;                    // 131072 float4 per slice
  int off   = i & 131071;
  float4 v = ((const float4*)pk)[i];
  U16x4 o{f2bf(v.x), f2bf(v.y), f2bf(v.z), f2bf(v.w)};
  ((U16x4*)(kcat + (size_t)slice*(4608*128)))[off] = o;
}

// transpose fp32 [M][N] (row stride lds_) -> bf16 [N][M] (row stride ldd), batched via z
__global__ void k_transpose(const float* __restrict__ src, u16* __restrict__ dst,
                            int lds_, int ldd, size_t sstride, size_t dstride){
  src += (size_t)blockIdx.z * sstride; dst += (size_t)blockIdx.z * dstride;
  __shared__ float tile[32][33];
  int bm = blockIdx.y*32, bn = blockIdx.x*32;
  int tx = threadIdx.x & 31, ty = threadIdx.x >> 5;
  #pragma unroll
  for (int r = 0; r < 32; r += 8)
    tile[r+ty][tx] = src[(size_t)(bm + r + ty)*lds_ + bn + tx];
  __syncthreads();
  #pragma unroll
  for (int r = 0; r < 32; r += 8)
    dst[(size_t)(bn + r + ty)*ldd + bm + tx] = f2bf(tile[tx][r+ty]);
}

// ---------------- bf16 GEMM: C[m][n] = sum_k A[m][k] * Bt[n][k] ----------------
// 128x128 tile, BK=64, 4 waves (each 64x64), reg-staged LDS with XOR swizzle.
__global__ __launch_bounds__(256) void k_gemm_bt(
    const u16* __restrict__ A, const u16* __restrict__ Bt, float* __restrict__ C,
    int N, int K)
{
  __shared__ __align__(16) u16 As[128*64];
  __shared__ __align__(16) u16 Bs[128*64];
  const int tid = threadIdx.x, lane = tid & 63, wave = tid >> 6;
  const int m0 = blockIdx.y*128, n0 = blockIdx.x*128;
  const int wr = (wave >> 1)*64, wc = (wave & 1)*64;
  const int srow = tid >> 3, sc8 = tid & 7;
  const u16* ap = A  + (size_t)(m0 + srow)*K + sc8*8;
  const u16* bp = Bt + (size_t)(n0 + srow)*K + sc8*8;
  floatx4 acc[4][4] = {};
  short8 ra[4], rb[4];
  #pragma unroll
  for (int i = 0; i < 4; ++i){
    ra[i] = *(const short8*)(ap + (size_t)i*32*K);
    rb[i] = *(const short8*)(bp + (size_t)i*32*K);
  }
  const int nk = K >> 6;
  for (int kt = 0; kt < nk; ++kt){
    #pragma unroll
    for (int i = 0; i < 4; ++i){
      const int r = srow + i*32;
      const int c = sc8 ^ (r & 7);
      *(short8*)(As + r*64 + c*8) = ra[i];
      *(short8*)(Bs + r*64 + c*8) = rb[i];
    }
    __syncthreads();
    if (kt + 1 < nk){
      const size_t ko = (size_t)(kt+1)*64;
      #pragma unroll
      for (int i = 0; i < 4; ++i){
        ra[i] = *(const short8*)(ap + (size_t)i*32*K + ko);
        rb[i] = *(const short8*)(bp + (size_t)i*32*K + ko);
      }
    }
    #pragma unroll
    for (int ks = 0; ks < 2; ++ks){
      const int c16 = ks*4 + (lane >> 4);
      short8 af[4], bf[4];
      #pragma unroll
      for (int mi = 0; mi < 4; ++mi){
        const int r = wr + mi*16 + (lane & 15);
        af[mi] = *(const short8*)(As + r*64 + ((c16 ^ (r & 7))*8));
      }
      #pragma unroll
      for (int ni = 0; ni < 4; ++ni){
        const int r = wc + ni*16 + (lane & 15);
        bf[ni] = *(const short8*)(Bs + r*64 + ((c16 ^ (r & 7))*8));
      }
      #pragma unroll
      for (int mi = 0; mi < 4; ++mi)
        #pragma unroll
        for (int ni = 0; ni < 4; ++ni)
          acc[mi][ni] = __builtin_amdgcn_mfma_f32_16x16x32_bf16(af[mi], bf[ni], acc[mi][ni], 0,0,0);
    }
    __syncthreads();
  }
  #pragma unroll
  for (int mi = 0; mi < 4; ++mi)
    #pragma unroll
    for (int ni = 0; ni < 4; ++ni){
      const int col = n0 + wc + ni*16 + (lane & 15);
      const int row = m0 + wr + mi*16 + ((lane >> 4) << 2);
      #pragma unroll
      for (int j = 0; j < 4; ++j)
        C[(size_t)(row + j)*N + col] = acc[mi][ni][j];
    }
}

// ---------------- RoPE ----------------
__global__ void k_rope_q(const float* __restrict__ qf, const float* __restrict__ cosb,
                         const float* __restrict__ sinb, const int* __restrict__ pid,
                         u16* __restrict__ qbo){
  int gid = blockIdx.x*256 + threadIdx.x;   // 2,097,152 = 1024*32*64
  int d = gid & 63, hh = (gid >> 6) & 31, m = gid >> 11;
  int b = m >> 9, t = m & 511;
  int p = pid[b*512 + t];
  float c = cosb[(size_t)p*128 + d], s = sinb[(size_t)p*128 + d];
  size_t ib = (size_t)m*4096 + hh*128 + d;
  float x = qf[ib], y = qf[ib + 64];
  const float sc = 0.08838834764831845f;    // 1/sqrt(128) folded into q
  size_t ob = (((size_t)(b*32 + hh))*512 + t)*128 + d;
  qbo[ob]      = f2bf((x*c - y*s)*sc);
  qbo[ob + 64] = f2bf((y*c + x*s)*sc);
}

__global__ void k_rope_kv(const float* __restrict__ kvf, const float* __restrict__ cosb,
                          const float* __restrict__ sinb, const int* __restrict__ pid,
                          u16* __restrict__ kcat, float* __restrict__ knr, u16* __restrict__ vtcat){
  int gid = blockIdx.x*256 + threadIdx.x;   // 524,288 = 1024*8*64
  int d = gid & 63, kv = (gid >> 6) & 7, m = gid >> 9;
  int b = m >> 9, t = m & 511;
  int p = pid[b*512 + t];
  float c = cosb[(size_t)p*128 + d], s = sinb[(size_t)p*128 + d];
  size_t ib = (size_t)m*2048 + kv*128 + d;
  float x = kvf[ib], y = kvf[ib + 64];
  float k0 = x*c - y*s, k1 = y*c + x*s;
  int bk = b*8 + kv;
  size_t kb = ((size_t)bk*4608 + 4096 + t)*128 + d;
  kcat[kb] = f2bf(k0); kcat[kb + 64] = f2bf(k1);
  size_t nb = ((size_t)bk*512 + t)*128 + d;
  knr[nb] = k0; knr[nb + 64] = k1;
  float v0 = kvf[ib + 1024], v1 = kvf[ib + 1088];
  size_t vb = (size_t)bk*(128*4608) + (size_t)d*4608 + 4096 + t;
  vtcat[vb] = f2bf(v0);
  vtcat[vb + (size_t)64*4608] = f2bf(v1);
}

// ---------------- fused attention ----------------
// grid 512 (xcd-swizzled -> b,kv,h,tb), block 256 (4 waves x 16 q-rows).
__global__ __launch_bounds__(256) void k_attn(
    const u16* __restrict__ qb, const u16* __restrict__ kcat,
    const u16* __restrict__ vtcat, u16* __restrict__ ctxb,
    float* __restrict__ part_sc)
{
  __shared__ __align__(16) u16 kvlds[64*128];   // K tile [64][128] then V tile [128][64]
  __shared__ __align__(16) float plds[64*68];
  __shared__ float cs[4608];

  const int tid = threadIdx.x, lane = tid & 63, wave = tid >> 6;
  const int bid = blockIdx.x;
  const int slice  = (bid & 7) + 8*((bid >> 3) >> 5);  // b*8+kv, one slice per XCD chunk
  const int within = (bid >> 3) & 31;
  const int b  = slice >> 3;
  const int kv = slice & 7;
  const int h  = kv*4 + (within >> 3);
  const int tb = within & 7;
  const int t0 = tb * 64;

  const u16* qp = qb + (((size_t)(b*32 + h))*512 + t0) * 128;
  const u16* kp = kcat  + (size_t)slice * (4608*128);
  const u16* vp = vtcat + (size_t)slice * (128*4608);

  for (int i = tid; i < 4608; i += 256) cs[i] = 0.f;

  short8 qf[4];
  {
    const int r = wave*16 + (lane & 15);
    const u16* q0 = qp + (size_t)r*128 + ((lane>>4)*8);
    #pragma unroll
    for (int ks = 0; ks < 4; ++ks) qf[ks] = *(const short8*)(q0 + ks*32);
  }

  const int ntiles = 65 + tb;
  float l0=0.f, l1=0.f, l2=0.f, l3=0.f;

  // ---- sweep 1: denominators ----
  for (int st = 0; st < ntiles; ++st){
    const int s0 = st * 64;
    __syncthreads();
    {
      const int c16 = tid & 15;
      #pragma unroll
      for (int i = 0; i < 4; ++i){
        const int row = i*16 + (tid >> 4);
        short8 v = *(const short8*)(kp + (size_t)(s0 + row)*128 + c16*8);
        *(short8*)(kvlds + row*128 + ((c16 ^ (row & 7))*8)) = v;
      }
    }
    __syncthreads();
    floatx4 sacc[4] = {};
    #pragma unroll
    for (int ks = 0; ks < 4; ++ks){
      const int c16 = ks*4 + (lane >> 4);
      #pragma unroll
      for (int nf = 0; nf < 4; ++nf){
        const int r = nf*16 + (lane & 15);
        short8 kf = *(const short8*)(kvlds + r*128 + ((c16 ^ (r & 7))*8));
        sacc[nf] = __builtin_amdgcn_mfma_f32_16x16x32_bf16(qf[ks], kf, sacc[nf], 0,0,0);
      }
    }
    const bool lastt = (st == ntiles-1);
    #pragma unroll
    for (int nf = 0; nf < 4; ++nf){
      #pragma unroll
      for (int j = 0; j < 4; ++j){
        float e = __expf(sacc[nf][j]);
        if (lastt){
          int scol = nf*16 + (lane & 15);
          int tloc = wave*16 + ((lane >> 4) << 2) + j;
          if (scol > tloc) e = 0.f;
        }
        if (j==0) l0 += e; else if (j==1) l1 += e; else if (j==2) l2 += e; else l3 += e;
      }
    }
  }
  #pragma unroll
  for (int m = 1; m <= 8; m <<= 1){
    l0 += __shfl_xor(l0, m); l1 += __shfl_xor(l1, m);
    l2 += __shfl_xor(l2, m); l3 += __shfl_xor(l3, m);
  }
  const float rl0 = 1.f/l0, rl1 = 1.f/l1, rl2 = 1.f/l2, rl3 = 1.f/l3;

  // ---- sweep 2: P, colsums, PV ----
  floatx4 pacc[8] = {};
  const int prow = wave*16 + (lane & 15);
  for (int st = 0; st < ntiles; ++st){
    const int s0 = st*64;
    __syncthreads();
    {
      const int c16 = tid & 15;
      #pragma unroll
      for (int i = 0; i < 4; ++i){
        const int row = i*16 + (tid >> 4);
        short8 v = *(const short8*)(kp + (size_t)(s0 + row)*128 + c16*8);
        *(short8*)(kvlds + row*128 + ((c16 ^ (row & 7))*8)) = v;
      }
    }
    __syncthreads();
    floatx4 sacc[4] = {};
    #pragma unroll
    for (int ks = 0; ks < 4; ++ks){
      const int c16 = ks*4 + (lane >> 4);
      #pragma unroll
      for (int nf = 0; nf < 4; ++nf){
        const int r = nf*16 + (lane & 15);
        short8 kf = *(const short8*)(kvlds + r*128 + ((c16 ^ (r & 7))*8));
        sacc[nf] = __builtin_amdgcn_mfma_f32_16x16x32_bf16(qf[ks], kf, sacc[nf], 0,0,0);
      }
    }
    const bool lastt = (st == ntiles-1);
    float cs0=0.f, cs1=0.f, cs2=0.f, cs3=0.f;
    #pragma unroll
    for (int nf = 0; nf < 4; ++nf){
      float cpart = 0.f;
      #pragma unroll
      for (int j = 0; j < 4; ++j){
        float e = __expf(sacc[nf][j]);
        if (lastt){
          int scol = nf*16 + (lane & 15);
          int tloc = wave*16 + ((lane >> 4) << 2) + j;
          if (scol > tloc) e = 0.f;
        }
        float rl = (j==0)?rl0:(j==1)?rl1:(j==2)?rl2:rl3;
        float p = e * rl;
        plds[(wave*16 + ((lane>>4)<<2) + j)*68 + nf*16 + (lane & 15)] = p;
        cpart += p;
      }
      if (nf==0) cs0=cpart; else if (nf==1) cs1=cpart; else if (nf==2) cs2=cpart; else cs3=cpart;
    }
    cs0 += __shfl_xor(cs0,16); cs0 += __shfl_xor(cs0,32);
    cs1 += __shfl_xor(cs1,16); cs1 += __shfl_xor(cs1,32);
    cs2 += __shfl_xor(cs2,16); cs2 += __shfl_xor(cs2,32);
    cs3 += __shfl_xor(cs3,16); cs3 += __shfl_xor(cs3,32);
    {
      const int nfsel = lane >> 4;
      float v = (nfsel==0)?cs0:(nfsel==1)?cs1:(nfsel==2)?cs2:cs3;
      atomicAdd(&cs[s0 + nfsel*16 + (lane & 15)], v);
    }
    __syncthreads();
    {
      const int c = tid & 7;
      #pragma unroll
      for (int i = 0; i < 4; ++i){
        const int row = i*32 + (tid >> 3);
        short8 v = *(const short8*)(vp + (size_t)row*4608 + s0 + c*8);
        *(short8*)(kvlds + row*64 + ((c ^ (row & 7))*8)) = v;
      }
    }
    __syncthreads();
    short8 pa[2];
    #pragma unroll
    for (int k2 = 0; k2 < 2; ++k2){
      const int sbase = k2*32 + ((lane>>4)*8);
      const float* pp = plds + prow*68 + sbase;
      float4 x = *(const float4*)pp;
      float4 y = *(const float4*)(pp + 4);
      short8 t8;
      t8[0]=(short)f2bf(x.x); t8[1]=(short)f2bf(x.y); t8[2]=(short)f2bf(x.z); t8[3]=(short)f2bf(x.w);
      t8[4]=(short)f2bf(y.x); t8[5]=(short)f2bf(y.y); t8[6]=(short)f2bf(y.z); t8[7]=(short)f2bf(y.w);
      pa[k2] = t8;
    }
    #pragma unroll
    for (int nf = 0; nf < 8; ++nf){
      const int rv = nf*16 + (lane & 15);
      #pragma unroll
      for (int k2 = 0; k2 < 2; ++k2){
        const int c = ((k2*4 + (lane>>4)) ^ (rv & 7));
        short8 vf = *(const short8*)(kvlds + rv*64 + c*8);
        pacc[nf] = __builtin_amdgcn_mfma_f32_16x16x32_bf16(pa[k2], vf, pacc[nf], 0,0,0);
      }
    }
  }
  #pragma unroll
  for (int nf = 0; nf < 8; ++nf)
    #pragma unroll
    for (int j = 0; j < 4; ++j){
      const int trow = t0 + wave*16 + ((lane>>4)<<2) + j;
      const int col  = h*128 + nf*16 + (lane & 15);
      ctxb[(size_t)(b*512 + trow)*4096 + col] = f2bf(pacc[nf][j]);
    }
  __syncthreads();
  {
    float* pr = part_sc + (((size_t)(b*32 + h))*8 + tb)*4608;
    for (int i = tid; i < 4608; i += 256) pr[i] = cs[i];
  }
}

// ---------------- hh = hh_prev + mean-over-group colsums ----------------
__global__ void k_hh_reduce(const float* __restrict__ part, const float* __restrict__ hhprev,
                            float* __restrict__ hh){
  int gid = blockIdx.x*256 + threadIdx.x;   // 73728
  if (gid >= 73728) return;
  int s = gid % 4608; int bk = gid / 4608; int b = bk >> 3, kv = bk & 7;
  float acc = 0.f;
  #pragma unroll
  for (int h4 = 0; h4 < 4; ++h4){
    const float* pp = part + (((size_t)(b*32 + kv*4 + h4))*8)*4608 + s;
    #pragma unroll
    for (int tbb = 0; tbb < 8; ++tbb) acc += pp[(size_t)tbb*4608];
  }
  acc *= 0.25f;
  if (s < 4096) acc += hhprev[(size_t)bk*4096 + s];
  hh[gid] = acc;
}

// ---------------- top-k per (b,kv): bitonic sort, write keep + hh_new ----------------
__global__ __launch_bounds__(256) void k_topk(const float* __restrict__ hh, int* __restrict__ keep,
                                              float* __restrict__ hh_new){
  __shared__ uint64_t keys[4096];
  __shared__ int sidx[512];
  const int bk = blockIdx.x, tid = threadIdx.x;
  const float* hp = hh + (size_t)bk*4608;
  for (int i = tid; i < 4096; i += 256){
    uint32_t vb = __float_as_uint(hp[i]);   // hh >= 0 -> monotonic bits
    keys[i] = ((uint64_t)(0xFFFFFFFFu - vb) << 12) | (uint32_t)i;
  }
  __syncthreads();
  for (int k = 2; k <= 4096; k <<= 1){
    for (int j = k >> 1; j > 0; j >>= 1){
      for (int i = tid; i < 4096; i += 256){
        int ixj = i ^ j;
        if (ixj > i){
          uint64_t a = keys[i], c = keys[ixj];
          bool up = ((i & k) == 0);
          if ((a > c) == up){ keys[i] = c; keys[ixj] = a; }
        }
      }
      __syncthreads();
    }
  }
  for (int i = tid; i < 512; i += 256) sidx[i] = (int)(keys[i] & 0xFFF);
  __syncthreads();
  for (int k = 2; k <= 512; k <<= 1){
    for (int j = k >> 1; j > 0; j >>= 1){
      for (int i = tid; i < 512; i += 256){
        int ixj = i ^ j;
        if (ixj > i){
          int a = sidx[i], c = sidx[ixj];
          bool up = ((i & k) == 0);
          if ((a > c) == up){ sidx[i] = c; sidx[ixj] = a; }
        }
      }
      __syncthreads();
    }
  }
  for (int i = tid; i < 512; i += 256){
    int id = sidx[i];
    keep[bk*1024 + i] = id;
    hh_new[(size_t)bk*1024 + i] = hp[id];
    keep[bk*1024 + 512 + i] = 4096 + i;
    hh_new[(size_t)bk*1024 + 512 + i] = hp[4096 + i];
  }
}

// ---------------- gather kept K/V rows (fp32 exact) ----------------
__global__ void k_gather(const float* __restrict__ pastk, const float* __restrict__ pastv,
                         const float* __restrict__ knr, const float* __restrict__ kvf,
                         const int* __restrict__ keep,
                         float* __restrict__ outk, float* __restrict__ outv){
  int r = blockIdx.x*2 + (threadIdx.x >> 7);
  int lane = threadIdx.x & 127;
  int bk = r >> 10, i = r & 1023;
  int idx = keep[bk*1024 + i];
  float kval, vval;
  if (idx < 4096){
    kval = pastk[((size_t)bk*4096 + idx)*128 + lane];
    vval = pastv[((size_t)bk*4096 + idx)*128 + lane];
  } else {
    int t = idx - 4096; int b = bk >> 3, kv = bk & 7;
    kval = knr[((size_t)bk*512 + t)*128 + lane];
    vval = kvf[(size_t)(b*512 + t)*2048 + 1024 + kv*128 + lane];
  }
  outk[(size_t)r*128 + lane] = kval;
  outv[(size_t)r*128 + lane] = vval;
}

// ---------------- launch ----------------
extern "C" void kernel_launch(void* const* d_in, const int* in_sizes, int n_in,
                              void* d_out, int out_size, void* d_ws, size_t ws_size,
                              hipStream_t stream){
  const float* hs     = (const float*)d_in[0];
  const float* pastk  = (const float*)d_in[1];
  const float* pastv  = (const float*)d_in[2];
  const float* hhprev = (const float*)d_in[3];
  const float* wq     = (const float*)d_in[4];
  const float* wk     = (const float*)d_in[5];
  const float* wv     = (const float*)d_in[6];
  const float* wo     = (const float*)d_in[7];
  const float* cosb   = (const float*)d_in[8];
  const float* sinb   = (const float*)d_in[9];
  const int*   pid    = (const int*)d_in[10];
  float* out = (float*)d_out;
  char* ws = (char*)d_ws;

  // workspace layout (bytes)
  u16*   hsb  = (u16*)(ws + 0);                       //  8,388,608
  u16*   wqt  = (u16*)(ws + 8388608);                 // 33,554,432 (reused for wo^T)
  u16*   wkvt = (u16*)(ws + 41943040);                // 16,777,216
  float* qf   = (float*)(ws + 58720256);              // 16,777,216 (reused for part_sc)
  float* part = qf;
  float* kvf  = (float*)(ws + 75497472);              //  8,388,608
  u16*   qb   = (u16*)(ws + 83886080);                //  8,388,608
  u16*   kcat = (u16*)(ws + 92274688);                // 18,874,368
  u16*   vtc  = (u16*)(ws + 111149056);               // 18,874,368
  float* knr  = (float*)(ws + 130023424);             //  8,388,608
  u16*   ctxb = (u16*)(ws + 138412032);               //  8,388,608
  float* hhb  = (float*)(ws + 146800640);             //    294,912
  int*   keep = (int*)(ws + 147095552);               //     65,536

  (void)in_sizes; (void)n_in; (void)out_size; (void)ws_size;

  k_convert<<<4096,256,0,stream>>>(hs, hsb, 1048576);
  k_transpose<<<dim3(128,128,1),256,0,stream>>>(wq, wqt, 4096, 4096, 0, 0);
  k_transpose<<<dim3(32,128,1),256,0,stream>>>(wk, wkvt, 1024, 4096, 0, 0);
  k_transpose<<<dim3(32,128,1),256,0,stream>>>(wv, wkvt + (size_t)1024*4096, 1024, 4096, 0, 0);
  k_transpose<<<dim3(4,128,16),256,0,stream>>>(pastv, vtc, 128, 4608,
                                               (size_t)4096*128, (size_t)128*4608);
  k_copy_pastk<<<8192,256,0,stream>>>(pastk, kcat);

  k_gemm_bt<<<dim3(32,8),256,0,stream>>>(hsb, wqt, qf, 4096, 4096);
  k_gemm_bt<<<dim3(16,8),256,0,stream>>>(hsb, wkvt, kvf, 2048, 4096);
  // wo^T into the (now free after q-GEMM) wqt buffer
  k_transpose<<<dim3(128,128,1),256,0,stream>>>(wo, wqt, 4096, 4096, 0, 0);

  k_rope_q<<<8192,256,0,stream>>>(qf, cosb, sinb, pid, qb);   // qf consumed before part reuse
  k_rope_kv<<<2048,256,0,stream>>>(kvf, cosb, sinb, pid, kcat, knr, vtc);

  k_attn<<<512,256,0,stream>>>(qb, kcat, vtc, ctxb, part);

  k_gemm_bt<<<dim3(32,8),256,0,stream>>>(ctxb, wqt, out, 4096, 4096);

  k_hh_reduce<<<288,256,0,stream>>>(part, hhprev, hhb);
  k_topk<<<16,256,0,stream>>>(hhb, keep, out + 8388608);
  k_gather<<<8192,256,0,stream>>>(pastk, pastv, knr, kvf, keep,
                                  out + 4194304, out + 6291456);
}

// Round 3
// 789.348 us; speedup vs baseline: 1.1484x; 1.1484x over previous
//
#include <hip/hip_runtime.h>
#include <cstdint>
#include <cstddef>

typedef unsigned short u16;
typedef __attribute__((ext_vector_type(8))) short short8;
typedef __attribute__((ext_vector_type(4))) float floatx4;

static __device__ __forceinline__ u16 f2bf(float f){
  union { float f; uint32_t i; } u; u.f = f;
  uint32_t i = u.i;
  return (u16)((i + 0x7FFFu + ((i >> 16) & 1u)) >> 16);
}

struct __align__(8) U16x4 { u16 a,b,c,d; };

// ---------------- elementwise fp32 -> bf16 ----------------
__global__ void k_convert(const float* __restrict__ src, u16* __restrict__ dst, int n4){
  int i = blockIdx.x*256 + threadIdx.x;
  if (i >= n4) return;
  float4 v = ((const float4*)src)[i];
  U16x4 o{f2bf(v.x), f2bf(v.y), f2bf(v.z), f2bf(v.w)};
  ((U16x4*)dst)[i] = o;
}

// past_k [16][4096][128] fp32 -> kcat [16][4608][128] bf16 rows 0..4095
__global__ void k_copy_pastk(const float* __restrict__ pk, u16* __restrict__ kcat){
  int i = blockIdx.x*256 + threadIdx.x;
  int slice = i >> 17;
  int off   = i & 131071;
  float4 v = ((const float4*)pk)[i];
  U16x4 o{f2bf(v.x), f2bf(v.y), f2bf(v.z), f2bf(v.w)};
  ((U16x4*)(kcat + (size_t)slice*(4608*128)))[off] = o;
}

// transpose fp32 [M][N] -> bf16 [N][M], batched via z
__global__ void k_transpose(const float* __restrict__ src, u16* __restrict__ dst,
                            int lds_, int ldd, size_t sstride, size_t dstride){
  src += (size_t)blockIdx.z * sstride; dst += (size_t)blockIdx.z * dstride;
  __shared__ float tile[32][33];
  int bm = blockIdx.y*32, bn = blockIdx.x*32;
  int tx = threadIdx.x & 31, ty = threadIdx.x >> 5;
  #pragma unroll
  for (int r = 0; r < 32; r += 8)
    tile[r+ty][tx] = src[(size_t)(bm + r + ty)*lds_ + bn + tx];
  __syncthreads();
  #pragma unroll
  for (int r = 0; r < 32; r += 8)
    dst[(size_t)(bn + r + ty)*ldd + bm + tx] = f2bf(tile[tx][r+ty]);
}

// ---------------- bf16 GEMM with split-K via blockIdx.z ----------------
__global__ __launch_bounds__(256) void k_gemm_bt(
    const u16* __restrict__ A, const u16* __restrict__ Bt, float* __restrict__ C,
    int N, int Kfull, int kLen, size_t cstride)
{
  __shared__ __align__(16) u16 As[128*64];
  __shared__ __align__(16) u16 Bs[128*64];
  const int tid = threadIdx.x, lane = tid & 63, wave = tid >> 6;
  const int m0 = blockIdx.y*128, n0 = blockIdx.x*128;
  const int kOff = blockIdx.z * kLen;
  C += (size_t)blockIdx.z * cstride;
  const int wr = (wave >> 1)*64, wc = (wave & 1)*64;
  const int srow = tid >> 3, sc8 = tid & 7;
  const u16* ap = A  + (size_t)(m0 + srow)*Kfull + kOff + sc8*8;
  const u16* bp = Bt + (size_t)(n0 + srow)*Kfull + kOff + sc8*8;
  floatx4 acc[4][4] = {};
  short8 ra[4], rb[4];
  #pragma unroll
  for (int i = 0; i < 4; ++i){
    ra[i] = *(const short8*)(ap + (size_t)i*32*Kfull);
    rb[i] = *(const short8*)(bp + (size_t)i*32*Kfull);
  }
  const int nk = kLen >> 6;
  for (int kt = 0; kt < nk; ++kt){
    #pragma unroll
    for (int i = 0; i < 4; ++i){
      const int r = srow + i*32;
      const int c = sc8 ^ (r & 7);
      *(short8*)(As + r*64 + c*8) = ra[i];
      *(short8*)(Bs + r*64 + c*8) = rb[i];
    }
    __syncthreads();
    if (kt + 1 < nk){
      const size_t ko = (size_t)(kt+1)*64;
      #pragma unroll
      for (int i = 0; i < 4; ++i){
        ra[i] = *(const short8*)(ap + (size_t)i*32*Kfull + ko);
        rb[i] = *(const short8*)(bp + (size_t)i*32*Kfull + ko);
      }
    }
    #pragma unroll
    for (int ks = 0; ks < 2; ++ks){
      const int c16 = ks*4 + (lane >> 4);
      short8 af[4], bf[4];
      #pragma unroll
      for (int mi = 0; mi < 4; ++mi){
        const int r = wr + mi*16 + (lane & 15);
        af[mi] = *(const short8*)(As + r*64 + ((c16 ^ (r & 7))*8));
      }
      #pragma unroll
      for (int ni = 0; ni < 4; ++ni){
        const int r = wc + ni*16 + (lane & 15);
        bf[ni] = *(const short8*)(Bs + r*64 + ((c16 ^ (r & 7))*8));
      }
      #pragma unroll
      for (int mi = 0; mi < 4; ++mi)
        #pragma unroll
        for (int ni = 0; ni < 4; ++ni)
          acc[mi][ni] = __builtin_amdgcn_mfma_f32_16x16x32_bf16(af[mi], bf[ni], acc[mi][ni], 0,0,0);
    }
    __syncthreads();
  }
  #pragma unroll
  for (int mi = 0; mi < 4; ++mi)
    #pragma unroll
    for (int ni = 0; ni < 4; ++ni){
      const int col = n0 + wc + ni*16 + (lane & 15);
      const int row = m0 + wr + mi*16 + ((lane >> 4) << 2);
      #pragma unroll
      for (int j = 0; j < 4; ++j)
        C[(size_t)(row + j)*N + col] = acc[mi][ni][j];
    }
}

__global__ void k_add(const float* __restrict__ a, const float* __restrict__ b,
                      float* __restrict__ o, int n4){
  int i = blockIdx.x*256 + threadIdx.x;
  if (i >= n4) return;
  float4 x = ((const float4*)a)[i], y = ((const float4*)b)[i];
  float4 z; z.x=x.x+y.x; z.y=x.y+y.y; z.z=x.z+y.z; z.w=x.w+y.w;
  ((float4*)o)[i] = z;
}

// ---------------- RoPE (sums split-K partials) ----------------
__global__ void k_rope_q(const float* __restrict__ qfA, const float* __restrict__ qfB,
                         const float* __restrict__ cosb, const float* __restrict__ sinb,
                         const int* __restrict__ pid, u16* __restrict__ qbo){
  int gid = blockIdx.x*256 + threadIdx.x;   // 2,097,152
  int d = gid & 63, hh = (gid >> 6) & 31, m = gid >> 11;
  int b = m >> 9, t = m & 511;
  int p = pid[b*512 + t];
  float c = cosb[(size_t)p*128 + d], s = sinb[(size_t)p*128 + d];
  size_t ib = (size_t)m*4096 + hh*128 + d;
  float x = qfA[ib] + qfB[ib], y = qfA[ib+64] + qfB[ib+64];
  const float sc = 0.08838834764831845f;
  size_t ob = (((size_t)(b*32 + hh))*512 + t)*128 + d;
  qbo[ob]      = f2bf((x*c - y*s)*sc);
  qbo[ob + 64] = f2bf((y*c + x*s)*sc);
}

__global__ void k_rope_kv(const float* __restrict__ kvfA, const float* __restrict__ kvfB,
                          const float* __restrict__ cosb, const float* __restrict__ sinb,
                          const int* __restrict__ pid,
                          u16* __restrict__ kcat, u16* __restrict__ vtcat){
  int gid = blockIdx.x*256 + threadIdx.x;   // 524,288
  int d = gid & 63, kv = (gid >> 6) & 7, m = gid >> 9;
  int b = m >> 9, t = m & 511;
  int p = pid[b*512 + t];
  float c = cosb[(size_t)p*128 + d], s = sinb[(size_t)p*128 + d];
  size_t ib = (size_t)m*2048 + kv*128 + d;
  float x = kvfA[ib] + kvfB[ib], y = kvfA[ib+64] + kvfB[ib+64];
  float k0 = x*c - y*s, k1 = y*c + x*s;
  int bk = b*8 + kv;
  size_t kb = ((size_t)bk*4608 + 4096 + t)*128 + d;
  kcat[kb] = f2bf(k0); kcat[kb + 64] = f2bf(k1);
  float v0 = kvfA[ib+1024] + kvfB[ib+1024];
  float v1 = kvfA[ib+1088] + kvfB[ib+1088];
  size_t vb = (size_t)bk*(128*4608) + (size_t)d*4608 + 4096 + t;
  vtcat[vb] = f2bf(v0);
  vtcat[vb + (size_t)64*4608] = f2bf(v1);
}

// ---------------- attention pass 1: row-sum denominators, s-split x4 ----------------
__global__ __launch_bounds__(256) void k_attn_l(
    const u16* __restrict__ qb, const u16* __restrict__ kcat,
    float* __restrict__ lpart)
{
  __shared__ __align__(16) u16 kl[64*128];
  const int tid = threadIdx.x, lane = tid & 63, wave = tid >> 6;
  const int bid = blockIdx.x;
  const int slice = (bid & 7) + 8*(bid >> 10);     // 2048 blocks
  const int within = (bid >> 3) & 127;
  const int b = slice >> 3, kv = slice & 7;
  const int h = kv*4 + (within >> 5);
  const int tb = (within >> 2) & 7;
  const int sc = within & 3;
  const int t0 = tb*64;
  const int ntiles = 65 + tb;
  const int st0 = sc*18;
  const int st1 = (st0 + 18 < ntiles) ? (st0 + 18) : ntiles;
  const u16* qp = qb + (((size_t)(b*32+h))*512 + t0)*128;
  const u16* kp = kcat + (size_t)slice*(4608*128);

  short8 qf[4];
  {
    const int r = wave*16 + (lane & 15);
    const u16* q0 = qp + (size_t)r*128 + ((lane>>4)*8);
    #pragma unroll
    for (int ks=0; ks<4; ++ks) qf[ks] = *(const short8*)(q0 + ks*32);
  }
  const int c16 = tid & 15, srow = tid >> 4;
  short8 rk[4];
  #pragma unroll
  for (int i=0;i<4;++i)
    rk[i] = *(const short8*)(kp + (size_t)(st0*64 + i*16 + srow)*128 + c16*8);

  float l0=0.f,l1=0.f,l2=0.f,l3=0.f;
  for (int st=st0; st<st1; ++st){
    __syncthreads();
    #pragma unroll
    for (int i=0;i<4;++i){
      const int row = i*16 + srow;
      *(short8*)(kl + row*128 + ((c16 ^ (row&7))*8)) = rk[i];
    }
    __syncthreads();
    if (st+1 < st1){
      #pragma unroll
      for (int i=0;i<4;++i)
        rk[i] = *(const short8*)(kp + (size_t)((st+1)*64 + i*16 + srow)*128 + c16*8);
    }
    floatx4 sacc[4] = {};
    #pragma unroll
    for (int ks=0; ks<4; ++ks){
      const int cc = ks*4 + (lane>>4);
      #pragma unroll
      for (int nf=0; nf<4; ++nf){
        const int r = nf*16 + (lane&15);
        short8 kf = *(const short8*)(kl + r*128 + ((cc ^ (r&7))*8));
        sacc[nf] = __builtin_amdgcn_mfma_f32_16x16x32_bf16(qf[ks], kf, sacc[nf], 0,0,0);
      }
    }
    const bool lastt = (st == ntiles-1);
    #pragma unroll
    for (int nf=0;nf<4;++nf)
      #pragma unroll
      for (int j=0;j<4;++j){
        float e = __expf(sacc[nf][j]);
        if (lastt){
          int scol = nf*16 + (lane&15);
          int tloc = wave*16 + ((lane>>4)<<2) + j;
          if (scol > tloc) e = 0.f;
        }
        if(j==0)l0+=e; else if(j==1)l1+=e; else if(j==2)l2+=e; else l3+=e;
      }
  }
  #pragma unroll
  for (int m=1; m<=8; m<<=1){
    l0 += __shfl_xor(l0,m); l1 += __shfl_xor(l1,m);
    l2 += __shfl_xor(l2,m); l3 += __shfl_xor(l3,m);
  }
  if ((lane & 15) == 0){
    float* lp = lpart + ((((size_t)(b*32+h))*8 + tb)<<8) + (sc<<6) + wave*16 + ((lane>>4)<<2);
    lp[0]=l0; lp[1]=l1; lp[2]=l2; lp[3]=l3;
  }
}

// ---------------- attention pass 2: P, colsums, PV ----------------
__global__ __launch_bounds__(256) void k_attn_pv(
    const u16* __restrict__ qb, const u16* __restrict__ kcat,
    const u16* __restrict__ vtcat, const float* __restrict__ lpart,
    u16* __restrict__ ctxb, float* __restrict__ part)
{
  __shared__ __align__(16) u16 kl[64*128];
  __shared__ __align__(16) u16 vl[128*64];
  __shared__ __align__(16) float plds[64*68];
  __shared__ float cw[4*64];

  const int tid=threadIdx.x, lane=tid&63, wave=tid>>6;
  const int bid=blockIdx.x;
  const int slice = (bid&7) + 8*((bid>>3)>>5);     // 512 blocks
  const int within = (bid>>3)&31;
  const int b=slice>>3, kv=slice&7;
  const int h = kv*4 + (within>>3);
  const int tb = within&7;
  const int t0 = tb*64;
  const int ntiles = 65+tb;
  const u16* qp = qb + (((size_t)(b*32+h))*512 + t0)*128;
  const u16* kp = kcat + (size_t)slice*(4608*128);
  const u16* vp = vtcat + (size_t)slice*(128*4608);
  float* pb = part + (((size_t)(b*32+h))*8 + tb)*4608;

  float rl[4];
  {
    const float* lp = lpart + ((((size_t)(b*32+h))*8 + tb)<<8);
    const int r0 = wave*16 + ((lane>>4)<<2);
    #pragma unroll
    for (int j=0;j<4;++j){
      int r = r0 + j;
      float l = lp[r] + lp[64+r] + lp[128+r] + lp[192+r];
      rl[j] = 1.f/l;
    }
  }
  short8 qf[4];
  {
    const int r = wave*16 + (lane & 15);
    const u16* q0 = qp + (size_t)r*128 + ((lane>>4)*8);
    #pragma unroll
    for (int ks=0; ks<4; ++ks) qf[ks] = *(const short8*)(q0 + ks*32);
  }
  const int c16 = tid&15, srow = tid>>4;
  const int vc = tid&7,  vrow = tid>>3;
  short8 rk[4], rv[4];
  #pragma unroll
  for (int i=0;i<4;++i){
    rk[i] = *(const short8*)(kp + (size_t)(i*16 + srow)*128 + c16*8);
    rv[i] = *(const short8*)(vp + (size_t)(i*32 + vrow)*4608 + vc*8);
  }
  floatx4 pacc[8] = {};
  const int prow = wave*16 + (lane&15);

  for (int st=0; st<ntiles; ++st){
    const int s0 = st*64;
    __syncthreads();
    if (st > 0 && tid < 64)
      pb[s0-64+tid] = cw[tid] + cw[64+tid] + cw[128+tid] + cw[192+tid];
    #pragma unroll
    for (int i=0;i<4;++i){
      const int row = i*16 + srow;
      *(short8*)(kl + row*128 + ((c16 ^ (row&7))*8)) = rk[i];
      const int vr = i*32 + vrow;
      *(short8*)(vl + vr*64 + ((vc ^ (vr&7))*8)) = rv[i];
    }
    __syncthreads();
    if (st+1 < ntiles){
      #pragma unroll
      for (int i=0;i<4;++i){
        rk[i] = *(const short8*)(kp + (size_t)((st+1)*64 + i*16 + srow)*128 + c16*8);
        rv[i] = *(const short8*)(vp + (size_t)(i*32 + vrow)*4608 + (st+1)*64 + vc*8);
      }
    }
    floatx4 sacc[4] = {};
    #pragma unroll
    for (int ks=0; ks<4; ++ks){
      const int cc = ks*4 + (lane>>4);
      #pragma unroll
      for (int nf=0; nf<4; ++nf){
        const int r = nf*16 + (lane&15);
        short8 kf = *(const short8*)(kl + r*128 + ((cc ^ (r&7))*8));
        sacc[nf] = __builtin_amdgcn_mfma_f32_16x16x32_bf16(qf[ks], kf, sacc[nf], 0,0,0);
      }
    }
    const bool lastt = (st==ntiles-1);
    float cs0=0.f, cs1=0.f, cs2=0.f, cs3=0.f;
    #pragma unroll
    for (int nf=0;nf<4;++nf){
      float cpart=0.f;
      #pragma unroll
      for (int j=0;j<4;++j){
        float e = __expf(sacc[nf][j]);
        if (lastt){
          int scol = nf*16 + (lane&15);
          int tloc = wave*16 + ((lane>>4)<<2) + j;
          if (scol > tloc) e = 0.f;
        }
        float p = e * rl[j];
        plds[(wave*16 + ((lane>>4)<<2) + j)*68 + nf*16 + (lane&15)] = p;
        cpart += p;
      }
      if(nf==0)cs0=cpart; else if(nf==1)cs1=cpart; else if(nf==2)cs2=cpart; else cs3=cpart;
    }
    cs0 += __shfl_xor(cs0,16); cs0 += __shfl_xor(cs0,32);
    cs1 += __shfl_xor(cs1,16); cs1 += __shfl_xor(cs1,32);
    cs2 += __shfl_xor(cs2,16); cs2 += __shfl_xor(cs2,32);
    cs3 += __shfl_xor(cs3,16); cs3 += __shfl_xor(cs3,32);
    {
      const int nfsel = lane >> 4;
      float v = (nfsel==0)?cs0:(nfsel==1)?cs1:(nfsel==2)?cs2:cs3;
      cw[wave*64 + nfsel*16 + (lane & 15)] = v;
    }
    short8 pa[2];
    #pragma unroll
    for (int k2 = 0; k2 < 2; ++k2){
      const int sbase = k2*32 + ((lane>>4)*8);
      const float* pp = plds + prow*68 + sbase;
      float4 x = *(const float4*)pp;
      float4 y = *(const float4*)(pp + 4);
      short8 t8;
      t8[0]=(short)f2bf(x.x); t8[1]=(short)f2bf(x.y); t8[2]=(short)f2bf(x.z); t8[3]=(short)f2bf(x.w);
      t8[4]=(short)f2bf(y.x); t8[5]=(short)f2bf(y.y); t8[6]=(short)f2bf(y.z); t8[7]=(short)f2bf(y.w);
      pa[k2] = t8;
    }
    #pragma unroll
    for (int nf = 0; nf < 8; ++nf){
      const int rv2 = nf*16 + (lane & 15);
      #pragma unroll
      for (int k2 = 0; k2 < 2; ++k2){
        const int c = ((k2*4 + (lane>>4)) ^ (rv2 & 7));
        short8 vf = *(const short8*)(vl + rv2*64 + c*8);
        pacc[nf] = __builtin_amdgcn_mfma_f32_16x16x32_bf16(pa[k2], vf, pacc[nf], 0,0,0);
      }
    }
  }
  __syncthreads();
  if (tid < 64)
    pb[(ntiles-1)*64 + tid] = cw[tid] + cw[64+tid] + cw[128+tid] + cw[192+tid];
  #pragma unroll
  for (int nf = 0; nf < 8; ++nf)
    #pragma unroll
    for (int j = 0; j < 4; ++j){
      const int trow = t0 + wave*16 + ((lane>>4)<<2) + j;
      const int col  = h*128 + nf*16 + (lane & 15);
      ctxb[(size_t)(b*512 + trow)*4096 + col] = f2bf(pacc[nf][j]);
    }
}

// ---------------- hh = hh_prev + mean-over-group colsums ----------------
__global__ void k_hh_reduce(const float* __restrict__ part, const float* __restrict__ hhprev,
                            float* __restrict__ hh){
  int gid = blockIdx.x*256 + threadIdx.x;   // 73728
  if (gid >= 73728) return;
  int s = gid % 4608; int bk = gid / 4608; int b = bk >> 3, kv = bk & 7;
  float acc = 0.f;
  #pragma unroll
  for (int h4 = 0; h4 < 4; ++h4){
    const float* pp = part + (((size_t)(b*32 + kv*4 + h4))*8)*4608 + s;
    #pragma unroll
    for (int tbb = 0; tbb < 8; ++tbb)
      if (s < 4160 + tbb*64) acc += pp[(size_t)tbb*4608];
  }
  acc *= 0.25f;
  if (s < 4096) acc += hhprev[(size_t)bk*4096 + s];
  hh[gid] = acc;
}

// ---------------- top-k per (b,kv) ----------------
__global__ __launch_bounds__(256) void k_topk(const float* __restrict__ hh, int* __restrict__ keep,
                                              float* __restrict__ hh_new){
  __shared__ uint64_t keys[4096];
  __shared__ int sidx[512];
  const int bk = blockIdx.x, tid = threadIdx.x;
  const float* hp = hh + (size_t)bk*4608;
  for (int i = tid; i < 4096; i += 256){
    uint32_t vb = __float_as_uint(hp[i]);
    keys[i] = ((uint64_t)(0xFFFFFFFFu - vb) << 12) | (uint32_t)i;
  }
  __syncthreads();
  for (int k = 2; k <= 4096; k <<= 1){
    for (int j = k >> 1; j > 0; j >>= 1){
      for (int i = tid; i < 4096; i += 256){
        int ixj = i ^ j;
        if (ixj > i){
          uint64_t a = keys[i], c = keys[ixj];
          bool up = ((i & k) == 0);
          if ((a > c) == up){ keys[i] = c; keys[ixj] = a; }
        }
      }
      __syncthreads();
    }
  }
  for (int i = tid; i < 512; i += 256) sidx[i] = (int)(keys[i] & 0xFFF);
  __syncthreads();
  for (int k = 2; k <= 512; k <<= 1){
    for (int j = k >> 1; j > 0; j >>= 1){
      for (int i = tid; i < 512; i += 256){
        int ixj = i ^ j;
        if (ixj > i){
          int a = sidx[i], c = sidx[ixj];
          bool up = ((i & k) == 0);
          if ((a > c) == up){ sidx[i] = c; sidx[ixj] = a; }
        }
      }
      __syncthreads();
    }
  }
  for (int i = tid; i < 512; i += 256){
    int id = sidx[i];
    keep[bk*1024 + i] = id;
    hh_new[(size_t)bk*1024 + i] = hp[id];
    keep[bk*1024 + 512 + i] = 4096 + i;
    hh_new[(size_t)bk*1024 + 512 + i] = hp[4096 + i];
  }
}

// ---------------- gather kept K/V rows (fp32 exact) ----------------
__global__ void k_gather(const float* __restrict__ pastk, const float* __restrict__ pastv,
                         const float* __restrict__ kvfA, const float* __restrict__ kvfB,
                         const float* __restrict__ cosb, const float* __restrict__ sinb,
                         const int* __restrict__ pid, const int* __restrict__ keep,
                         float* __restrict__ outk, float* __restrict__ outv){
  int r = blockIdx.x*2 + (threadIdx.x >> 7);
  int d = threadIdx.x & 127;
  int bk = r >> 10, i = r & 1023;
  int idx = keep[bk*1024 + i];
  float kval, vval;
  if (idx < 4096){
    kval = pastk[((size_t)bk*4096 + idx)*128 + d];
    vval = pastv[((size_t)bk*4096 + idx)*128 + d];
  } else {
    int t = idx - 4096; int b = bk >> 3, kv = bk & 7;
    size_t base = ((size_t)(b*512 + t))*2048 + kv*128;
    int dp = (d < 64) ? d + 64 : d - 64;
    float x  = kvfA[base + d]  + kvfB[base + d];
    float xp = kvfA[base + dp] + kvfB[base + dp];
    int p = pid[b*512 + t];
    float c = cosb[(size_t)p*128 + d], s = sinb[(size_t)p*128 + d];
    kval = x*c + xp*((d < 64) ? -s : s);
    vval = kvfA[base + 1024 + d] + kvfB[base + 1024 + d];
  }
  outk[(size_t)r*128 + d] = kval;
  outv[(size_t)r*128 + d] = vval;
}

// ---------------- launch ----------------
extern "C" void kernel_launch(void* const* d_in, const int* in_sizes, int n_in,
                              void* d_out, int out_size, void* d_ws, size_t ws_size,
                              hipStream_t stream){
  const float* hs     = (const float*)d_in[0];
  const float* pastk  = (const float*)d_in[1];
  const float* pastv  = (const float*)d_in[2];
  const float* hhprev = (const float*)d_in[3];
  const float* wq     = (const float*)d_in[4];
  const float* wk     = (const float*)d_in[5];
  const float* wv     = (const float*)d_in[6];
  const float* wo     = (const float*)d_in[7];
  const float* cosb   = (const float*)d_in[8];
  const float* sinb   = (const float*)d_in[9];
  const int*   pid    = (const int*)d_in[10];
  float* out = (float*)d_out;
  char* ws = (char*)d_ws;

  u16*   hsb  = (u16*)(ws + 0);                       //  8,388,608
  u16*   wqt  = (u16*)(ws + 8388608);                 // 33,554,432 (reused for wo^T)
  u16*   wkvt = (u16*)(ws + 41943040);                // 16,777,216
  float* qfA  = (float*)(ws + 58720256);              // 16,777,216 (later outA)
  float* qfB  = (float*)(ws + 75497472);              // 16,777,216 (later outB)
  float* kvfA = (float*)(ws + 92274688);              //  8,388,608
  float* kvfB = (float*)(ws + 100663296);             //  8,388,608
  u16*   qb   = (u16*)(ws + 109051904);               //  8,388,608
  u16*   kcat = (u16*)(ws + 117440512);               // 18,874,368
  u16*   vtc  = (u16*)(ws + 136314880);               // 18,874,368
  u16*   ctxb = (u16*)(ws + 155189248);               //  8,388,608
  float* part = (float*)(ws + 163577856);             //  9,437,184
  float* lprt = (float*)(ws + 173015040);             //    524,288
  float* hhb  = (float*)(ws + 173539328);             //    294,912
  int*   keep = (int*)(ws + 173834240);               //     65,536

  (void)in_sizes; (void)n_in; (void)out_size; (void)ws_size;

  k_convert<<<4096,256,0,stream>>>(hs, hsb, 1048576);
  k_transpose<<<dim3(128,128,1),256,0,stream>>>(wq, wqt, 4096, 4096, 0, 0);
  k_transpose<<<dim3(32,128,1),256,0,stream>>>(wk, wkvt, 1024, 4096, 0, 0);
  k_transpose<<<dim3(32,128,1),256,0,stream>>>(wv, wkvt + (size_t)1024*4096, 1024, 4096, 0, 0);
  k_transpose<<<dim3(4,128,16),256,0,stream>>>(pastv, vtc, 128, 4608,
                                               (size_t)4096*128, (size_t)128*4608);
  k_copy_pastk<<<8192,256,0,stream>>>(pastk, kcat);

  k_gemm_bt<<<dim3(32,8,2),256,0,stream>>>(hsb, wqt, qfA, 4096, 4096, 2048, (size_t)1024*4096);
  k_gemm_bt<<<dim3(16,8,2),256,0,stream>>>(hsb, wkvt, kvfA, 2048, 4096, 2048, (size_t)1024*2048);
  k_transpose<<<dim3(128,128,1),256,0,stream>>>(wo, wqt, 4096, 4096, 0, 0);

  k_rope_q<<<8192,256,0,stream>>>(qfA, qfB, cosb, sinb, pid, qb);
  k_rope_kv<<<2048,256,0,stream>>>(kvfA, kvfB, cosb, sinb, pid, kcat, vtc);

  k_attn_l<<<2048,256,0,stream>>>(qb, kcat, lprt);
  k_attn_pv<<<512,256,0,stream>>>(qb, kcat, vtc, lprt, ctxb, part);

  // o-GEMM partials into qfA/qfB region (dead after rope_q)
  k_gemm_bt<<<dim3(32,8,2),256,0,stream>>>(ctxb, wqt, qfA, 4096, 4096, 2048, (size_t)1024*4096);
  k_add<<<4096,256,0,stream>>>(qfA, qfB, out, 1048576);

  k_hh_reduce<<<288,256,0,stream>>>(part, hhprev, hhb);
  k_topk<<<16,256,0,stream>>>(hhb, keep, out + 8388608);
  k_gather<<<8192,256,0,stream>>>(pastk, pastv, kvfA, kvfB, cosb, sinb, pid, keep,
                                  out + 4194304, out + 6291456);
}

// Round 8
// 725.594 us; speedup vs baseline: 1.2493x; 1.0879x over previous
//
#include <hip/hip_runtime.h>
#include <cstdint>
#include <cstddef>

typedef unsigned short u16;
typedef __attribute__((ext_vector_type(8))) short short8;
typedef __attribute__((ext_vector_type(4))) float floatx4;

static __device__ __forceinline__ u16 f2bf(float f){
  union { float f; uint32_t i; } u; u.f = f;
  uint32_t i = u.i;
  return (u16)((i + 0x7FFFu + ((i >> 16) & 1u)) >> 16);
}

static __device__ __forceinline__ void gload_lds16(const u16* g, u16* l){
  __builtin_amdgcn_global_load_lds(
      (const __attribute__((address_space(1))) uint32_t*)g,
      (__attribute__((address_space(3))) uint32_t*)l, 16, 0, 0);
}

static __device__ __forceinline__ uint32_t cvtpk(float lo, float hi){
  uint32_t r;
  asm("v_cvt_pk_bf16_f32 %0, %1, %2" : "=v"(r) : "v"(lo), "v"(hi));
  return r;
}

struct __align__(8) U16x4 { u16 a,b,c,d; };
union PU { short8 s; uint32_t u[4]; };

// ---------------- elementwise fp32 -> bf16 ----------------
__global__ void k_convert(const float* __restrict__ src, u16* __restrict__ dst, int n4){
  int i = blockIdx.x*256 + threadIdx.x;
  if (i >= n4) return;
  float4 v = ((const float4*)src)[i];
  U16x4 o{f2bf(v.x), f2bf(v.y), f2bf(v.z), f2bf(v.w)};
  ((U16x4*)dst)[i] = o;
}

// past_k [16][4096][128] fp32 -> kcat [16][4608][128] bf16 rows 0..4095
__global__ void k_copy_pastk(const float* __restrict__ pk, u16* __restrict__ kcat){
  int i = blockIdx.x*256 + threadIdx.x;
  int slice = i >> 17;
  int off   = i & 131071;
  float4 v = ((const float4*)pk)[i];
  U16x4 o{f2bf(v.x), f2bf(v.y), f2bf(v.z), f2bf(v.w)};
  ((U16x4*)(kcat + (size_t)slice*(4608*128)))[off] = o;
}

// transpose fp32 [M][N] -> bf16 [N][M], batched via z
__global__ void k_transpose(const float* __restrict__ src, u16* __restrict__ dst,
                            int lds_, int ldd, size_t sstride, size_t dstride){
  src += (size_t)blockIdx.z * sstride; dst += (size_t)blockIdx.z * dstride;
  __shared__ float tile[32][33];
  int bm = blockIdx.y*32, bn = blockIdx.x*32;
  int tx = threadIdx.x & 31, ty = threadIdx.x >> 5;
  #pragma unroll
  for (int r = 0; r < 32; r += 8)
    tile[r+ty][tx] = src[(size_t)(bm + r + ty)*lds_ + bn + tx];
  __syncthreads();
  #pragma unroll
  for (int r = 0; r < 32; r += 8)
    dst[(size_t)(bn + r + ty)*ldd + bm + tx] = f2bf(tile[tx][r+ty]);
}

// ---------------- bf16 GEMM, split-K, global_load_lds staging ----------------
// LDS dest linear-in-lane; XOR swizzle applied by pre-swizzling the GLOBAL column.
__global__ __launch_bounds__(256) void k_gemm_bt(
    const u16* __restrict__ A, const u16* __restrict__ Bt, float* __restrict__ C,
    int N, int Kfull, int kLen, size_t cstride)
{
  __shared__ __align__(16) u16 As[128*64];
  __shared__ __align__(16) u16 Bs[128*64];
  const int tid = threadIdx.x, lane = tid & 63, wave = tid >> 6;
  const int m0 = blockIdx.y*128, n0 = blockIdx.x*128;
  const int kOff = blockIdx.z * kLen;
  C += (size_t)blockIdx.z * cstride;
  const int wr = (wave >> 1)*64, wc = (wave & 1)*64;
  const int srow = tid >> 3, sc8 = tid & 7;
  const int csw = (sc8 ^ (srow & 7)) * 8;         // pre-swizzled source column
  const u16* ap = A  + (size_t)(m0 + srow)*Kfull + kOff + csw;
  const u16* bp = Bt + (size_t)(n0 + srow)*Kfull + kOff + csw;
  u16* la = As + wave*512;                         // linear dest: lane*16B auto
  u16* lb = Bs + wave*512;
  floatx4 acc[4][4] = {};
  const int nk = kLen >> 6;
  for (int kt = 0; kt < nk; ++kt){
    if (kt) __syncthreads();
    const size_t ko = (size_t)kt*64;
    #pragma unroll
    for (int i = 0; i < 4; ++i){
      gload_lds16(ap + (size_t)i*32*Kfull + ko, la + i*2048);
      gload_lds16(bp + (size_t)i*32*Kfull + ko, lb + i*2048);
    }
    __syncthreads();
    #pragma unroll
    for (int ks = 0; ks < 2; ++ks){
      const int c16 = ks*4 + (lane >> 4);
      short8 af[4], bf[4];
      #pragma unroll
      for (int mi = 0; mi < 4; ++mi){
        const int r = wr + mi*16 + (lane & 15);
        af[mi] = *(const short8*)(As + r*64 + ((c16 ^ (r & 7))*8));
      }
      #pragma unroll
      for (int ni = 0; ni < 4; ++ni){
        const int r = wc + ni*16 + (lane & 15);
        bf[ni] = *(const short8*)(Bs + r*64 + ((c16 ^ (r & 7))*8));
      }
      #pragma unroll
      for (int mi = 0; mi < 4; ++mi)
        #pragma unroll
        for (int ni = 0; ni < 4; ++ni)
          acc[mi][ni] = __builtin_amdgcn_mfma_f32_16x16x32_bf16(af[mi], bf[ni], acc[mi][ni], 0,0,0);
    }
  }
  #pragma unroll
  for (int mi = 0; mi < 4; ++mi)
    #pragma unroll
    for (int ni = 0; ni < 4; ++ni){
      const int col = n0 + wc + ni*16 + (lane & 15);
      const int row = m0 + wr + mi*16 + ((lane >> 4) << 2);
      #pragma unroll
      for (int j = 0; j < 4; ++j)
        C[(size_t)(row + j)*N + col] = acc[mi][ni][j];
    }
}

__global__ void k_add(const float* __restrict__ a, const float* __restrict__ b,
                      float* __restrict__ o, int n4){
  int i = blockIdx.x*256 + threadIdx.x;
  if (i >= n4) return;
  float4 x = ((const float4*)a)[i], y = ((const float4*)b)[i];
  float4 z; z.x=x.x+y.x; z.y=x.y+y.y; z.z=x.z+y.z; z.w=x.w+y.w;
  ((float4*)o)[i] = z;
}

__global__ void k_ctx_combine(const float* __restrict__ a, const float* __restrict__ b,
                              u16* __restrict__ o, int n4){
  int i = blockIdx.x*256 + threadIdx.x;
  if (i >= n4) return;
  float4 x = ((const float4*)a)[i], y = ((const float4*)b)[i];
  U16x4 r{f2bf(x.x+y.x), f2bf(x.y+y.y), f2bf(x.z+y.z), f2bf(x.w+y.w)};
  ((U16x4*)o)[i] = r;
}

// ---------------- RoPE (sums split-K partials) ----------------
__global__ void k_rope_q(const float* __restrict__ qfA, const float* __restrict__ qfB,
                         const float* __restrict__ cosb, const float* __restrict__ sinb,
                         const int* __restrict__ pid, u16* __restrict__ qbo){
  int gid = blockIdx.x*256 + threadIdx.x;   // 2,097,152
  int d = gid & 63, hh = (gid >> 6) & 31, m = gid >> 11;
  int b = m >> 9, t = m & 511;
  int p = pid[b*512 + t];
  float c = cosb[(size_t)p*128 + d], s = sinb[(size_t)p*128 + d];
  size_t ib = (size_t)m*4096 + hh*128 + d;
  float x = qfA[ib] + qfB[ib], y = qfA[ib+64] + qfB[ib+64];
  const float sc = 0.08838834764831845f;
  size_t ob = (((size_t)(b*32 + hh))*512 + t)*128 + d;
  qbo[ob]      = f2bf((x*c - y*s)*sc);
  qbo[ob + 64] = f2bf((y*c + x*s)*sc);
}

__global__ void k_rope_kv(const float* __restrict__ kvfA, const float* __restrict__ kvfB,
                          const float* __restrict__ cosb, const float* __restrict__ sinb,
                          const int* __restrict__ pid,
                          u16* __restrict__ kcat, u16* __restrict__ vtcat){
  int gid = blockIdx.x*256 + threadIdx.x;   // 524,288
  int d = gid & 63, kv = (gid >> 6) & 7, m = gid >> 9;
  int b = m >> 9, t = m & 511;
  int p = pid[b*512 + t];
  float c = cosb[(size_t)p*128 + d], s = sinb[(size_t)p*128 + d];
  size_t ib = (size_t)m*2048 + kv*128 + d;
  float x = kvfA[ib] + kvfB[ib], y = kvfA[ib+64] + kvfB[ib+64];
  float k0 = x*c - y*s, k1 = y*c + x*s;
  int bk = b*8 + kv;
  size_t kb = ((size_t)bk*4608 + 4096 + t)*128 + d;
  kcat[kb] = f2bf(k0); kcat[kb + 64] = f2bf(k1);
  float v0 = kvfA[ib+1024] + kvfB[ib+1024];
  float v1 = kvfA[ib+1088] + kvfB[ib+1088];
  size_t vb = (size_t)bk*(128*4608) + (size_t)d*4608 + 4096 + t;
  vtcat[vb] = f2bf(v0);
  vtcat[vb + (size_t)64*4608] = f2bf(v1);
}

// ---------------- attention pass 1: row-sum denominators, s-split x4 ----------------
__global__ __launch_bounds__(256) void k_attn_l(
    const u16* __restrict__ qb, const u16* __restrict__ kcat,
    float* __restrict__ lpart)
{
  __shared__ __align__(16) u16 kl[64*128];
  const int tid = threadIdx.x, lane = tid & 63, wave = tid >> 6;
  const int bid = blockIdx.x;
  const int slice = (bid & 7) + 8*(bid >> 10);     // 2048 blocks
  const int within = (bid >> 3) & 127;
  const int b = slice >> 3, kv = slice & 7;
  const int h = kv*4 + (within >> 5);
  const int tb = (within >> 2) & 7;
  const int sc = within & 3;
  const int t0 = tb*64;
  const int ntiles = 65 + tb;
  const int st0 = sc*18;
  const int st1 = (st0 + 18 < ntiles) ? (st0 + 18) : ntiles;
  const u16* qp = qb + (((size_t)(b*32+h))*512 + t0)*128;
  const u16* kp = kcat + (size_t)slice*(4608*128);

  short8 qf[4];
  {
    const int r = wave*16 + (lane & 15);
    const u16* q0 = qp + (size_t)r*128 + ((lane>>4)*8);
    #pragma unroll
    for (int ks=0; ks<4; ++ks) qf[ks] = *(const short8*)(q0 + ks*32);
  }
  const int c16 = tid & 15, srow = tid >> 4;
  short8 rk[4];
  #pragma unroll
  for (int i=0;i<4;++i)
    rk[i] = *(const short8*)(kp + (size_t)(st0*64 + i*16 + srow)*128 + c16*8);

  float l0=0.f,l1=0.f,l2=0.f,l3=0.f;
  for (int st=st0; st<st1; ++st){
    __syncthreads();
    #pragma unroll
    for (int i=0;i<4;++i){
      const int row = i*16 + srow;
      *(short8*)(kl + row*128 + ((c16 ^ (row&7))*8)) = rk[i];
    }
    __syncthreads();
    if (st+1 < st1){
      #pragma unroll
      for (int i=0;i<4;++i)
        rk[i] = *(const short8*)(kp + (size_t)((st+1)*64 + i*16 + srow)*128 + c16*8);
    }
    floatx4 sacc[4] = {};
    #pragma unroll
    for (int ks=0; ks<4; ++ks){
      const int cc = ks*4 + (lane>>4);
      #pragma unroll
      for (int nf=0; nf<4; ++nf){
        const int r = nf*16 + (lane&15);
        short8 kf = *(const short8*)(kl + r*128 + ((cc ^ (r&7))*8));
        sacc[nf] = __builtin_amdgcn_mfma_f32_16x16x32_bf16(qf[ks], kf, sacc[nf], 0,0,0);
      }
    }
    const bool lastt = (st == ntiles-1);
    #pragma unroll
    for (int nf=0;nf<4;++nf)
      #pragma unroll
      for (int j=0;j<4;++j){
        float e = __expf(sacc[nf][j]);
        if (lastt){
          int scol = nf*16 + (lane&15);
          int tloc = wave*16 + ((lane>>4)<<2) + j;
          if (scol > tloc) e = 0.f;
        }
        if(j==0)l0+=e; else if(j==1)l1+=e; else if(j==2)l2+=e; else l3+=e;
      }
  }
  #pragma unroll
  for (int m=1; m<=8; m<<=1){
    l0 += __shfl_xor(l0,m); l1 += __shfl_xor(l1,m);
    l2 += __shfl_xor(l2,m); l3 += __shfl_xor(l3,m);
  }
  if ((lane & 15) == 0){
    float* lp = lpart + ((((size_t)(b*32+h))*8 + tb)<<8) + (sc<<6) + wave*16 + ((lane>>4)<<2);
    lp[0]=l0; lp[1]=l1; lp[2]=l2; lp[3]=l3;
  }
}

// ---------------- attention pass 2: P, colsums, PV — s-split x2, fp32 ctx partials --------
__global__ __launch_bounds__(256) void k_attn_pv(
    const u16* __restrict__ qb, const u16* __restrict__ kcat,
    const u16* __restrict__ vtcat, const float* __restrict__ lpart,
    float* __restrict__ ctxp, float* __restrict__ part)
{
  __shared__ __align__(16) u16 kl[64*128];
  __shared__ __align__(16) u16 vl[128*64];
  __shared__ __align__(16) float plds[64*68];
  __shared__ float cw[4*64];

  const int tid=threadIdx.x, lane=tid&63, wave=tid>>6;
  const int bid=blockIdx.x;
  const int slice = (bid&7) + 8*((bid>>3)>>6);     // 1024 blocks, same-slice -> same XCD
  const int within = (bid>>3)&63;
  const int b=slice>>3, kv=slice&7;
  const int h  = kv*4 + (within>>4);
  const int tb = (within>>1)&7;
  const int hlf = within&1;
  const int t0 = tb*64;
  const int ntiles = 65+tb;
  const int st0 = hlf ? 33 : 0;
  const int st1 = hlf ? ntiles : 33;
  const u16* qp = qb + (((size_t)(b*32+h))*512 + t0)*128;
  const u16* kp = kcat + (size_t)slice*(4608*128);
  const u16* vp = vtcat + (size_t)slice*(128*4608);
  float* pb = part + (((size_t)(b*32+h))*8 + tb)*4608;
  float* cp = ctxp + (size_t)hlf*4194304;

  float rl[4];
  {
    const float* lp = lpart + ((((size_t)(b*32+h))*8 + tb)<<8);
    const int r0 = wave*16 + ((lane>>4)<<2);
    #pragma unroll
    for (int j=0;j<4;++j){
      int r = r0 + j;
      float l = lp[r] + lp[64+r] + lp[128+r] + lp[192+r];
      rl[j] = 1.f/l;
    }
  }
  short8 qf[4];
  {
    const int r = wave*16 + (lane & 15);
    const u16* q0 = qp + (size_t)r*128 + ((lane>>4)*8);
    #pragma unroll
    for (int ks=0; ks<4; ++ks) qf[ks] = *(const short8*)(q0 + ks*32);
  }
  const int c16 = tid&15, srow = tid>>4;
  const int vc = tid&7,  vrow = tid>>3;
  short8 rk[4], rv[4];
  #pragma unroll
  for (int i=0;i<4;++i){
    rk[i] = *(const short8*)(kp + (size_t)(st0*64 + i*16 + srow)*128 + c16*8);
    rv[i] = *(const short8*)(vp + (size_t)(i*32 + vrow)*4608 + st0*64 + vc*8);
  }
  floatx4 pacc[8] = {};
  const int prow = wave*16 + (lane&15);

  for (int st=st0; st<st1; ++st){
    const int s0 = st*64;
    __syncthreads();
    if (st > st0 && tid < 64)
      pb[s0-64+tid] = cw[tid] + cw[64+tid] + cw[128+tid] + cw[192+tid];
    #pragma unroll
    for (int i=0;i<4;++i){
      const int row = i*16 + srow;
      *(short8*)(kl + row*128 + ((c16 ^ (row&7))*8)) = rk[i];
      const int vr = i*32 + vrow;
      *(short8*)(vl + vr*64 + ((vc ^ (vr&7))*8)) = rv[i];
    }
    __syncthreads();
    if (st+1 < st1){
      #pragma unroll
      for (int i=0;i<4;++i){
        rk[i] = *(const short8*)(kp + (size_t)((st+1)*64 + i*16 + srow)*128 + c16*8);
        rv[i] = *(const short8*)(vp + (size_t)(i*32 + vrow)*4608 + (st+1)*64 + vc*8);
      }
    }
    floatx4 sacc[4] = {};
    #pragma unroll
    for (int ks=0; ks<4; ++ks){
      const int cc = ks*4 + (lane>>4);
      #pragma unroll
      for (int nf=0; nf<4; ++nf){
        const int r = nf*16 + (lane&15);
        short8 kf = *(const short8*)(kl + r*128 + ((cc ^ (r&7))*8));
        sacc[nf] = __builtin_amdgcn_mfma_f32_16x16x32_bf16(qf[ks], kf, sacc[nf], 0,0,0);
      }
    }
    const bool lastt = (st==ntiles-1);
    float cs0=0.f, cs1=0.f, cs2=0.f, cs3=0.f;
    #pragma unroll
    for (int nf=0;nf<4;++nf){
      float cpart=0.f;
      #pragma unroll
      for (int j=0;j<4;++j){
        float e = __expf(sacc[nf][j]);
        if (lastt){
          int scol = nf*16 + (lane&15);
          int tloc = wave*16 + ((lane>>4)<<2) + j;
          if (scol > tloc) e = 0.f;
        }
        float p = e * rl[j];
        plds[(wave*16 + ((lane>>4)<<2) + j)*68 + nf*16 + (lane&15)] = p;
        cpart += p;
      }
      if(nf==0)cs0=cpart; else if(nf==1)cs1=cpart; else if(nf==2)cs2=cpart; else cs3=cpart;
    }
    cs0 += __shfl_xor(cs0,16); cs0 += __shfl_xor(cs0,32);
    cs1 += __shfl_xor(cs1,16); cs1 += __shfl_xor(cs1,32);
    cs2 += __shfl_xor(cs2,16); cs2 += __shfl_xor(cs2,32);
    cs3 += __shfl_xor(cs3,16); cs3 += __shfl_xor(cs3,32);
    {
      const int nfsel = lane >> 4;
      float v = (nfsel==0)?cs0:(nfsel==1)?cs1:(nfsel==2)?cs2:cs3;
      cw[wave*64 + nfsel*16 + (lane & 15)] = v;
    }
    short8 pa[2];
    #pragma unroll
    for (int k2 = 0; k2 < 2; ++k2){
      const float* pp = plds + prow*68 + k2*32 + ((lane>>4)*8);
      float4 x = *(const float4*)pp;
      float4 y = *(const float4*)(pp + 4);
      PU t;
      t.u[0] = cvtpk(x.x, x.y);
      t.u[1] = cvtpk(x.z, x.w);
      t.u[2] = cvtpk(y.x, y.y);
      t.u[3] = cvtpk(y.z, y.w);
      pa[k2] = t.s;
    }
    #pragma unroll
    for (int nf = 0; nf < 8; ++nf){
      const int rv2 = nf*16 + (lane & 15);
      #pragma unroll
      for (int k2 = 0; k2 < 2; ++k2){
        const int c = ((k2*4 + (lane>>4)) ^ (rv2 & 7));
        short8 vf = *(const short8*)(vl + rv2*64 + c*8);
        pacc[nf] = __builtin_amdgcn_mfma_f32_16x16x32_bf16(pa[k2], vf, pacc[nf], 0,0,0);
      }
    }
  }
  __syncthreads();
  if (tid < 64)
    pb[(st1-1)*64 + tid] = cw[tid] + cw[64+tid] + cw[128+tid] + cw[192+tid];
  #pragma unroll
  for (int nf = 0; nf < 8; ++nf)
    #pragma unroll
    for (int j = 0; j < 4; ++j){
      const int trow = t0 + wave*16 + ((lane>>4)<<2) + j;
      const int col  = h*128 + nf*16 + (lane & 15);
      cp[(size_t)(b*512 + trow)*4096 + col] = pacc[nf][j];
    }
}

// ---------------- hh = hh_prev + mean-over-group colsums ----------------
__global__ void k_hh_reduce(const float* __restrict__ part, const float* __restrict__ hhprev,
                            float* __restrict__ hh){
  int gid = blockIdx.x*256 + threadIdx.x;   // 73728
  if (gid >= 73728) return;
  int s = gid % 4608; int bk = gid / 4608; int b = bk >> 3, kv = bk & 7;
  float acc = 0.f;
  #pragma unroll
  for (int h4 = 0; h4 < 4; ++h4){
    const float* pp = part + (((size_t)(b*32 + kv*4 + h4))*8)*4608 + s;
    #pragma unroll
    for (int tbb = 0; tbb < 8; ++tbb)
      if (s < 4160 + tbb*64) acc += pp[(size_t)tbb*4608];
  }
  acc *= 0.25f;
  if (s < 4096) acc += hhprev[(size_t)bk*4096 + s];
  hh[gid] = acc;
}

// ---------------- top-512-of-4096 per (b,kv): radix select on packed u64 key ------------
// key = (~valbits)<<12 | idx  -> 512 smallest keys == jax top_k set (value desc, idx asc).
__global__ __launch_bounds__(256) void k_topk(const float* __restrict__ hh, int* __restrict__ keep,
                                              float* __restrict__ hh_new){
  __shared__ uint64_t keys[4096];
  __shared__ int hist[256];
  __shared__ int tsum[256];
  __shared__ uint64_t sprefix;
  __shared__ int srank;
  const int bk = blockIdx.x, tid = threadIdx.x;
  const float* hp = hh + (size_t)bk*4608;
  for (int i = tid; i < 4096; i += 256){
    uint32_t vb = __float_as_uint(hp[i]);   // hh >= 0 -> bits monotonic in value
    keys[i] = ((uint64_t)(0xFFFFFFFFu - vb) << 12) | (uint32_t)i;
  }
  if (tid == 0){ sprefix = 0; srank = 512; }
  __syncthreads();
  for (int shift = 40; shift >= 0; shift -= 8){
    hist[tid] = 0;
    __syncthreads();
    const uint64_t pref = sprefix;
    const uint64_t hm = ~((1ull << (shift+8)) - 1ull);
    for (int i = tid; i < 4096; i += 256){
      uint64_t k = keys[i];
      if ((k & hm) == pref) atomicAdd(&hist[(int)((k >> shift) & 255)], 1);
    }
    __syncthreads();
    if (tid == 0){
      int r = srank, b = 0;
      for (;;){ int c = hist[b]; if (r <= c) break; r -= c; ++b; }
      srank = r; sprefix = pref | ((uint64_t)b << shift);
    }
    __syncthreads();
  }
  const uint64_t kstar = sprefix;        // exact 512th-smallest key (keys distinct)
  const int base = tid*16;
  int cnt = 0;
  #pragma unroll
  for (int j = 0; j < 16; ++j) cnt += (keys[base+j] <= kstar) ? 1 : 0;
  tsum[tid] = cnt;
  __syncthreads();
  for (int off = 1; off < 256; off <<= 1){
    int v = (tid >= off) ? tsum[tid-off] : 0;
    __syncthreads();
    tsum[tid] += v;
    __syncthreads();
  }
  int pos = tsum[tid] - cnt;
  for (int j = 0; j < 16; ++j){
    uint64_t k = keys[base+j];
    if (k <= kstar){
      keep[bk*1024 + pos] = base + j;
      hh_new[(size_t)bk*1024 + pos] = __uint_as_float(0xFFFFFFFFu - (uint32_t)(k >> 12));
      ++pos;
    }
  }
  for (int i = tid; i < 512; i += 256){
    keep[bk*1024 + 512 + i] = 4096 + i;
    hh_new[(size_t)bk*1024 + 512 + i] = hp[4096 + i];
  }
}

// ---------------- gather kept K/V rows (fp32 exact) ----------------
__global__ void k_gather(const float* __restrict__ pastk, const float* __restrict__ pastv,
                         const float* __restrict__ kvfA, const float* __restrict__ kvfB,
                         const float* __restrict__ cosb, const float* __restrict__ sinb,
                         const int* __restrict__ pid, const int* __restrict__ keep,
                         float* __restrict__ outk, float* __restrict__ outv){
  int r = blockIdx.x*2 + (threadIdx.x >> 7);
  int d = threadIdx.x & 127;
  int bk = r >> 10, i = r & 1023;
  int idx = keep[bk*1024 + i];
  float kval, vval;
  if (idx < 4096){
    kval = pastk[((size_t)bk*4096 + idx)*128 + d];
    vval = pastv[((size_t)bk*4096 + idx)*128 + d];
  } else {
    int t = idx - 4096; int b = bk >> 3, kv = bk & 7;
    size_t base = ((size_t)(b*512 + t))*2048 + kv*128;
    int dp = (d < 64) ? d + 64 : d - 64;
    float x  = kvfA[base + d]  + kvfB[base + d];
    float xp = kvfA[base + dp] + kvfB[base + dp];
    int p = pid[b*512 + t];
    float c = cosb[(size_t)p*128 + d], s = sinb[(size_t)p*128 + d];
    kval = x*c + xp*((d < 64) ? -s : s);
    vval = kvfA[base + 1024 + d] + kvfB[base + 1024 + d];
  }
  outk[(size_t)r*128 + d] = kval;
  outv[(size_t)r*128 + d] = vval;
}

// ---------------- launch ----------------
extern "C" void kernel_launch(void* const* d_in, const int* in_sizes, int n_in,
                              void* d_out, int out_size, void* d_ws, size_t ws_size,
                              hipStream_t stream){
  const float* hs     = (const float*)d_in[0];
  const float* pastk  = (const float*)d_in[1];
  const float* pastv  = (const float*)d_in[2];
  const float* hhprev = (const float*)d_in[3];
  const float* wq     = (const float*)d_in[4];
  const float* wk     = (const float*)d_in[5];
  const float* wv     = (const float*)d_in[6];
  const float* wo     = (const float*)d_in[7];
  const float* cosb   = (const float*)d_in[8];
  const float* sinb   = (const float*)d_in[9];
  const int*   pid    = (const int*)d_in[10];
  float* out = (float*)d_out;
  char* ws = (char*)d_ws;

  u16*   hsb  = (u16*)(ws + 0);                       //  8,388,608
  u16*   wqt  = (u16*)(ws + 8388608);                 // 33,554,432 (reused for wo^T)
  u16*   wkvt = (u16*)(ws + 41943040);                // 16,777,216
  float* qfA  = (float*)(ws + 58720256);              // 16,777,216 (q partial A -> ctx partial A -> o partial A)
  float* qfB  = (float*)(ws + 75497472);              // 16,777,216 (q partial B -> ctx partial B -> o partial B)
  float* kvfA = (float*)(ws + 92274688);              //  8,388,608
  float* kvfB = (float*)(ws + 100663296);             //  8,388,608
  u16*   qb   = (u16*)(ws + 109051904);               //  8,388,608
  u16*   kcat = (u16*)(ws + 117440512);               // 18,874,368
  u16*   vtc  = (u16*)(ws + 136314880);               // 18,874,368
  u16*   ctxb = (u16*)(ws + 155189248);               //  8,388,608
  float* part = (float*)(ws + 163577856);             //  9,437,184
  float* lprt = (float*)(ws + 173015040);             //    524,288
  float* hhb  = (float*)(ws + 173539328);             //    294,912
  int*   keep = (int*)(ws + 173834240);               //     65,536

  (void)in_sizes; (void)n_in; (void)out_size; (void)ws_size;

  k_convert<<<4096,256,0,stream>>>(hs, hsb, 1048576);
  k_transpose<<<dim3(128,128,1),256,0,stream>>>(wq, wqt, 4096, 4096, 0, 0);
  k_transpose<<<dim3(32,128,1),256,0,stream>>>(wk, wkvt, 1024, 4096, 0, 0);
  k_transpose<<<dim3(32,128,1),256,0,stream>>>(wv, wkvt + (size_t)1024*4096, 1024, 4096, 0, 0);
  k_transpose<<<dim3(4,128,16),256,0,stream>>>(pastv, vtc, 128, 4608,
                                               (size_t)4096*128, (size_t)128*4608);
  k_copy_pastk<<<8192,256,0,stream>>>(pastk, kcat);

  k_gemm_bt<<<dim3(32,8,2),256,0,stream>>>(hsb, wqt, qfA, 4096, 4096, 2048, (size_t)1024*4096);
  k_gemm_bt<<<dim3(16,8,2),256,0,stream>>>(hsb, wkvt, kvfA, 2048, 4096, 2048, (size_t)1024*2048);
  k_transpose<<<dim3(128,128,1),256,0,stream>>>(wo, wqt, 4096, 4096, 0, 0);

  k_rope_q<<<8192,256,0,stream>>>(qfA, qfB, cosb, sinb, pid, qb);
  k_rope_kv<<<2048,256,0,stream>>>(kvfA, kvfB, cosb, sinb, pid, kcat, vtc);

  k_attn_l<<<2048,256,0,stream>>>(qb, kcat, lprt);
  k_attn_pv<<<1024,256,0,stream>>>(qb, kcat, vtc, lprt, qfA, part);
  k_ctx_combine<<<4096,256,0,stream>>>(qfA, qfB, ctxb, 1048576);

  k_gemm_bt<<<dim3(32,8,2),256,0,stream>>>(ctxb, wqt, qfA, 4096, 4096, 2048, (size_t)1024*4096);
  k_add<<<4096,256,0,stream>>>(qfA, qfB, out, 1048576);

  k_hh_reduce<<<288,256,0,stream>>>(part, hhprev, hhb);
  k_topk<<<16,256,0,stream>>>(hhb, keep, out + 8388608);
  k_gather<<<8192,256,0,stream>>>(pastk, pastv, kvfA, kvfB, cosb, sinb, pid, keep,
                                  out + 4194304, out + 6291456);
}